// Round 1
// baseline (1594.354 us; speedup 1.0000x reference)
//
#include <hip/hip_runtime.h>
#include <hip/hip_bf16.h>
#include <math.h>

typedef unsigned long long ull;

#define EPS 1e-5

// ---------------------------------------------------------------------------
// Weight packing: conv weights (Cout, Cin, 3, 3) f32 -> words [co][ky][kx][kc]
// bit b of word kc corresponds to ci = kc*64+b ; bit = (w > 0)
// ---------------------------------------------------------------------------
__global__ void pack_conv_w(const float* __restrict__ w, ull* __restrict__ out,
                            int Cout, int Cin) {
    int KC = Cin >> 6;
    int idx = blockIdx.x * 256 + threadIdx.x;
    int total = Cout * 9 * KC;
    if (idx >= total) return;
    int kc = idx % KC;
    int t = idx / KC;          // co*9 + tap
    int tap = t % 9;
    int co = t / 9;
    int ky = tap / 3, kx = tap % 3;
    const float* base = w + (size_t)co * Cin * 9 + ky * 3 + kx;
    ull bits = 0;
    for (int b = 0; b < 64; ++b) {
        float val = base[(size_t)(kc * 64 + b) * 9];
        if (val > 0.f) bits |= (1ull << b);
    }
    out[idx] = bits;
}

// lw1 (1024, 8192) packed to match A6 layout: word wi = s*8+kc (s=y*4+x),
// bit b <-> c = kc*64+b, flat k = c*16 + s
__global__ void pack_lw1(const float* __restrict__ w, ull* __restrict__ out) {
    int idx = blockIdx.x * 256 + threadIdx.x;  // co*128 + wi
    if (idx >= 1024 * 128) return;
    int wi = idx & 127, co = idx >> 7;
    int s = wi >> 3, kc = wi & 7;
    ull bits = 0;
    for (int b = 0; b < 64; ++b) {
        int c = kc * 64 + b;
        int k = c * 16 + s;
        if (w[(size_t)co * 8192 + k] > 0.f) bits |= (1ull << b);
    }
    out[idx] = bits;
}

// linear packing for lw2 (1024x1024) and lw3 (10x1024): word wi, bit b <-> k = wi*64+b
__global__ void pack_lw_lin(const float* __restrict__ w, ull* __restrict__ out,
                            int rows, int KCIN) {
    int idx = blockIdx.x * 256 + threadIdx.x;  // co*KCIN + wi
    if (idx >= rows * KCIN) return;
    int wi = idx % KCIN, co = idx / KCIN;
    ull bits = 0;
    for (int b = 0; b < 64; ++b) {
        if (w[(size_t)co * (KCIN * 64) + wi * 64 + b] > 0.f) bits |= (1ull << b);
    }
    out[idx] = bits;
}

// ---------------------------------------------------------------------------
// Conv1: real input x (32,3,32,32), binarized weights (384,3,3,3), fp64 acc.
// One block per pixel (n,y,x), 384 threads = one output channel each.
// Emits packed sign bits of ht(bn(conv+bias)) -> [n][y][x][kc] (kc=6 words).
// ---------------------------------------------------------------------------
__global__ __launch_bounds__(384) void conv1_bn_sign(
    const float* __restrict__ x, const float* __restrict__ cw,
    const float* __restrict__ cb, const float* __restrict__ g,
    const float* __restrict__ bb, const float* __restrict__ m,
    const float* __restrict__ v, ull* __restrict__ out) {
    int pix = blockIdx.x;            // n*1024 + y*32 + xx
    int xx = pix & 31, yy = (pix >> 5) & 31, n = pix >> 10;
    int co = threadIdx.x;
    double acc = 0.0;
    for (int ci = 0; ci < 3; ++ci) {
        for (int ky = 0; ky < 3; ++ky) {
            int iy = yy + ky - 1;
            if ((unsigned)iy >= 32u) continue;
            for (int kx = 0; kx < 3; ++kx) {
                int ix = xx + kx - 1;
                if ((unsigned)ix >= 32u) continue;
                float xv = x[(((size_t)n * 3 + ci) * 32 + iy) * 32 + ix];
                float wv = cw[(((size_t)co * 3 + ci) * 3 + ky) * 3 + kx];
                acc += (wv > 0.f) ? (double)xv : ((wv < 0.f) ? -(double)xv : 0.0);
            }
        }
    }
    double t = (acc + (double)cb[co] - (double)m[co]) *
                   ((double)g[co] / sqrt((double)v[co] + EPS)) +
               (double)bb[co];
    ull mask = __ballot(t > 0.0);
    if ((threadIdx.x & 63) == 0) out[(size_t)pix * 6 + (threadIdx.x >> 6)] = mask;
}

// ---------------------------------------------------------------------------
// Binary conv (+optional fused 2x2 maxpool) + bias + BN threshold + sign-pack.
// Grid: one block per POOLED output pixel (n, yo, xo). Block = 256 threads,
// looping over Cout in chunks of 256; each wave ballots 64 channels -> 1 word.
// Integer-exact: dot = Cin_valid_taps - 2*popc(a^w), padding taps skipped.
// Pool is applied to raw integer conv outputs (bias/BN after), matching ref.
// ---------------------------------------------------------------------------
template <int KC, int POOL>
__global__ __launch_bounds__(256) void binconv_kernel(
    const ull* __restrict__ act, const ull* __restrict__ wgt,
    const float* __restrict__ cb, const float* __restrict__ g,
    const float* __restrict__ bb, const float* __restrict__ m,
    const float* __restrict__ v, ull* __restrict__ out,
    int N, int Hin, int Win, int Cout) {
    const int Hout = Hin / POOL, Wout = Win / POOL;
    int pix = blockIdx.x;
    int xo = pix % Wout;
    int t = pix / Wout;
    int yo = t % Hout;
    int n = t / Hout;
    int KCOUT = Cout >> 6;
    (void)N;

    for (int j = 0; j < Cout; j += 256) {
        int co = j + (int)threadIdx.x;
        if (co < Cout) {  // wave-uniform (Cout % 64 == 0)
            int tot[POOL * POOL];
#pragma unroll
            for (int p = 0; p < POOL * POOL; ++p) tot[p] = 0;

            for (int ky = 0; ky < 3; ++ky) {
                for (int kx = 0; kx < 3; ++kx) {
                    ull w[KC];
                    const ull* wp = wgt + ((size_t)co * 9 + ky * 3 + kx) * KC;
#pragma unroll
                    for (int kc = 0; kc < KC; ++kc) w[kc] = wp[kc];
#pragma unroll
                    for (int p = 0; p < POOL * POOL; ++p) {
                        int dy = p / POOL, dx = p % POOL;
                        int iy = yo * POOL + dy + ky - 1;
                        int ix = xo * POOL + dx + kx - 1;
                        if ((unsigned)iy < (unsigned)Hin && (unsigned)ix < (unsigned)Win) {
                            const ull* ap = act + (((size_t)n * Hin + iy) * Win + ix) * KC;
                            int mism = 0;
#pragma unroll
                            for (int kc = 0; kc < KC; ++kc)
                                mism += __popcll(ap[kc] ^ w[kc]);
                            tot[p] += 64 * KC - 2 * mism;
                        }
                    }
                }
            }
            int best = tot[0];
#pragma unroll
            for (int p = 1; p < POOL * POOL; ++p) best = max(best, tot[p]);

            double tt = ((double)best + (double)cb[co] - (double)m[co]) *
                            ((double)g[co] / sqrt((double)v[co] + EPS)) +
                        (double)bb[co];
            ull mask = __ballot(tt > 0.0);
            if (((int)threadIdx.x & 63) == 0)
                out[(size_t)pix * KCOUT + ((unsigned)co >> 6)] = mask;
        }
    }
}

// ---------------------------------------------------------------------------
// Binary FC + bias + BN threshold + sign-pack. Grid = N blocks, 256 threads.
// ---------------------------------------------------------------------------
template <int KCIN>
__global__ __launch_bounds__(256) void binfc_kernel(
    const ull* __restrict__ act, const ull* __restrict__ wgt,
    const float* __restrict__ lb, const float* __restrict__ g,
    const float* __restrict__ bb, const float* __restrict__ m,
    const float* __restrict__ v, ull* __restrict__ out, int Cout) {
    int n = blockIdx.x;
    const ull* ap = act + (size_t)n * KCIN;
    for (int j = 0; j < Cout; j += 256) {
        int co = j + (int)threadIdx.x;
        if (co < Cout) {
            int mism = 0;
#pragma unroll 8
            for (int kc = 0; kc < KCIN; ++kc)
                mism += __popcll(ap[kc] ^ wgt[(size_t)co * KCIN + kc]);
            int dot = 64 * KCIN - 2 * mism;
            double tt = ((double)dot + (double)lb[co] - (double)m[co]) *
                            ((double)g[co] / sqrt((double)v[co] + EPS)) +
                        (double)bb[co];
            ull mask = __ballot(tt > 0.0);
            if (((int)threadIdx.x & 63) == 0)
                out[(size_t)n * (Cout >> 6) + ((unsigned)co >> 6)] = mask;
        }
    }
}

// ---------------------------------------------------------------------------
// Final FC3 (1024 -> 10) + affine-free BN + log_softmax, fp64. Grid = N.
// ---------------------------------------------------------------------------
__global__ __launch_bounds__(64) void fc3_softmax(
    const ull* __restrict__ act, const ull* __restrict__ wgt,
    const float* __restrict__ lb, const float* __restrict__ m9,
    const float* __restrict__ v9, float* __restrict__ out) {
    int n = blockIdx.x;
    __shared__ double z[10];
    int j = threadIdx.x;
    if (j < 10) {
        const ull* ap = act + (size_t)n * 16;
        int mism = 0;
#pragma unroll
        for (int kc = 0; kc < 16; ++kc) mism += __popcll(ap[kc] ^ wgt[j * 16 + kc]);
        int dot = 1024 - 2 * mism;
        z[j] = ((double)dot + (double)lb[j] - (double)m9[j]) /
               sqrt((double)v9[j] + EPS);
    }
    __syncthreads();
    if (j < 10) {
        double mx = z[0];
        for (int k = 1; k < 10; ++k) mx = fmax(mx, z[k]);
        double s = 0.0;
        for (int k = 0; k < 10; ++k) s += exp(z[k] - mx);
        out[n * 10 + j] = (float)(z[j] - mx - log(s));
    }
}

// ---------------------------------------------------------------------------
extern "C" void kernel_launch(void* const* d_in, const int* in_sizes, int n_in,
                              void* d_out, int out_size, void* d_ws, size_t ws_size,
                              hipStream_t stream) {
    (void)in_sizes; (void)n_in; (void)out_size; (void)ws_size;

    const float* x   = (const float*)d_in[0];
    const float* cw[6], *cbv[6];
    for (int i = 0; i < 6; ++i) {
        cw[i]  = (const float*)d_in[1 + 2 * i];
        cbv[i] = (const float*)d_in[2 + 2 * i];
    }
    const float *G[8], *B[8], *M[8], *V[8];
    for (int i = 0; i < 8; ++i) {
        G[i] = (const float*)d_in[13 + 4 * i];
        B[i] = (const float*)d_in[14 + 4 * i];
        M[i] = (const float*)d_in[15 + 4 * i];
        V[i] = (const float*)d_in[16 + 4 * i];
    }
    const float* m9  = (const float*)d_in[45];
    const float* v9  = (const float*)d_in[46];
    const float* lw1 = (const float*)d_in[47];
    const float* lb1 = (const float*)d_in[48];
    const float* lw2 = (const float*)d_in[49];
    const float* lb2 = (const float*)d_in[50];
    const float* lw3 = (const float*)d_in[51];
    const float* lb3 = (const float*)d_in[52];
    float* outp = (float*)d_out;

    ull* ws = (ull*)d_ws;
    // word offsets (8B units)
    ull* W2  = ws + 0;        // 20736
    ull* W3  = ws + 20736;    // 41472
    ull* W4  = ws + 62208;    // 82944
    ull* W5  = ws + 145152;   // 165888
    ull* W6  = ws + 311040;   // 110592
    ull* FW1 = ws + 421632;   // 131072
    ull* FW2 = ws + 552704;   // 16384
    ull* FW3 = ws + 569088;   // 160
    ull* A1  = ws + 569248;   // 196608 : 32x32x32 pixels x 6 words
    ull* A2  = ws + 765856;   // 49152  : 32x16x16 x 6
    ull* A3  = ws + 815008;   // 98304  : 32x16x16 x 12
    ull* A4  = ws + 913312;   // 24576  : 32x8x8 x 12
    ull* A5  = ws + 937888;   // 49152  : 32x8x8 x 24
    ull* A6  = ws + 987040;   // 4096   : 32x4x4 x 8
    ull* F1  = ws + 991136;   // 512    : 32 x 16
    ull* F2  = ws + 991648;   // 512    : 32 x 16
    // total 992160 words = ~7.94 MB

    // ---- pack weights ----
    pack_conv_w<<<(20736 + 255) / 256, 256, 0, stream>>>(cw[1], W2, 384, 384);
    pack_conv_w<<<(41472 + 255) / 256, 256, 0, stream>>>(cw[2], W3, 768, 384);
    pack_conv_w<<<(82944 + 255) / 256, 256, 0, stream>>>(cw[3], W4, 768, 768);
    pack_conv_w<<<(165888 + 255) / 256, 256, 0, stream>>>(cw[4], W5, 1536, 768);
    pack_conv_w<<<(110592 + 255) / 256, 256, 0, stream>>>(cw[5], W6, 512, 1536);
    pack_lw1<<<(131072 + 255) / 256, 256, 0, stream>>>(lw1, FW1);
    pack_lw_lin<<<(16384 + 255) / 256, 256, 0, stream>>>(lw2, FW2, 1024, 16);
    pack_lw_lin<<<1, 256, 0, stream>>>(lw3, FW3, 10, 16);

    // ---- layer 1: real conv, fp64 ----
    conv1_bn_sign<<<32 * 32 * 32, 384, 0, stream>>>(x, cw[0], cbv[0], G[0], B[0],
                                                    M[0], V[0], A1);
    // ---- binary conv stack ----
    binconv_kernel<6, 2><<<32 * 16 * 16, 256, 0, stream>>>(
        A1, W2, cbv[1], G[1], B[1], M[1], V[1], A2, 32, 32, 32, 384);
    binconv_kernel<6, 1><<<32 * 16 * 16, 256, 0, stream>>>(
        A2, W3, cbv[2], G[2], B[2], M[2], V[2], A3, 32, 16, 16, 768);
    binconv_kernel<12, 2><<<32 * 8 * 8, 256, 0, stream>>>(
        A3, W4, cbv[3], G[3], B[3], M[3], V[3], A4, 32, 16, 16, 768);
    binconv_kernel<12, 1><<<32 * 8 * 8, 256, 0, stream>>>(
        A4, W5, cbv[4], G[4], B[4], M[4], V[4], A5, 32, 8, 8, 1536);
    binconv_kernel<24, 2><<<32 * 4 * 4, 256, 0, stream>>>(
        A5, W6, cbv[5], G[5], B[5], M[5], V[5], A6, 32, 8, 8, 512);
    // ---- FC stack ----
    binfc_kernel<128><<<32, 256, 0, stream>>>(A6, FW1, lb1, G[6], B[6], M[6], V[6],
                                              F1, 1024);
    binfc_kernel<16><<<32, 256, 0, stream>>>(F1, FW2, lb2, G[7], B[7], M[7], V[7],
                                             F2, 1024);
    fc3_softmax<<<32, 64, 0, stream>>>(F2, FW3, lb3, m9, v9, outp);
}

// Round 2
// 689.701 us; speedup vs baseline: 2.3117x; 2.3117x over previous
//
#include <hip/hip_runtime.h>
#include <hip/hip_bf16.h>
#include <math.h>

typedef unsigned long long ull;

#define EPS 1e-5

// ---------------------------------------------------------------------------
// Weight packing: conv weights (Cout, Cin, 3, 3) f32 -> words [tap][kc][co]
// (co-major innermost so binconv weight loads are lane-coalesced).
// bit b of word kc corresponds to ci = kc*64+b ; bit = (w > 0)
// ---------------------------------------------------------------------------
__global__ void pack_conv_w(const float* __restrict__ w, ull* __restrict__ out,
                            int Cout, int Cin) {
    int KC = Cin >> 6;
    int idx = blockIdx.x * 256 + threadIdx.x;
    int total = Cout * 9 * KC;
    if (idx >= total) return;
    int kc = idx % KC;
    int t = idx / KC;          // co*9 + tap
    int tap = t % 9;
    int co = t / 9;
    int ky = tap / 3, kx = tap % 3;
    const float* base = w + (size_t)co * Cin * 9 + ky * 3 + kx;
    ull bits = 0;
    for (int b = 0; b < 64; ++b) {
        float val = base[(size_t)(kc * 64 + b) * 9];
        if (val > 0.f) bits |= (1ull << b);
    }
    out[((size_t)tap * KC + kc) * Cout + co] = bits;
}

// lw1 (1024, 8192) packed to match A6 layout: logical word wi = s*8+kc
// (s=y*4+x), bit b <-> c = kc*64+b, flat k = c*16 + s. Stored [wi][co].
__global__ void pack_lw1(const float* __restrict__ w, ull* __restrict__ out) {
    int idx = blockIdx.x * 256 + threadIdx.x;  // co*128 + wi
    if (idx >= 1024 * 128) return;
    int wi = idx & 127, co = idx >> 7;
    int s = wi >> 3, kc = wi & 7;
    ull bits = 0;
    for (int b = 0; b < 64; ++b) {
        int c = kc * 64 + b;
        int k = c * 16 + s;
        if (w[(size_t)co * 8192 + k] > 0.f) bits |= (1ull << b);
    }
    out[(size_t)wi * 1024 + co] = bits;
}

// linear packing for lw2 (1024x1024) and lw3 (10x1024): stored [wi][co],
// bit b <-> k = wi*64+b
__global__ void pack_lw_lin(const float* __restrict__ w, ull* __restrict__ out,
                            int rows, int KCIN) {
    int idx = blockIdx.x * 256 + threadIdx.x;  // co*KCIN + wi
    if (idx >= rows * KCIN) return;
    int wi = idx % KCIN, co = idx / KCIN;
    ull bits = 0;
    for (int b = 0; b < 64; ++b) {
        if (w[(size_t)co * (KCIN * 64) + wi * 64 + b] > 0.f) bits |= (1ull << b);
    }
    out[(size_t)wi * rows + co] = bits;
}

// ---------------------------------------------------------------------------
// Conv1: real input x (32,3,32,32), binarized weights (384,3,3,3), fp64 acc.
// One block per (n, row): x window staged in LDS (as fp64, zero-padded),
// 384 threads = one output channel each, sweeping 32 pixels.
// Emits packed sign bits of ht(bn(conv+bias)) -> [n][y][x][kc] (kc=6 words).
// ---------------------------------------------------------------------------
__global__ __launch_bounds__(384) void conv1_bn_sign(
    const float* __restrict__ x, const float* __restrict__ cw,
    const float* __restrict__ cb, const float* __restrict__ g,
    const float* __restrict__ bb, const float* __restrict__ m,
    const float* __restrict__ v, ull* __restrict__ out) {
    __shared__ double xs[3][3][34];   // [ci][ky][col+1], zero-padded cols/rows
    int blk = blockIdx.x;             // n*32 + y
    int y = blk & 31, n = blk >> 5;
    for (int i = threadIdx.x; i < 3 * 3 * 34; i += 384) {
        int col = i % 34;
        int r = i / 34;
        int ky = r % 3, ci = r / 3;
        int iy = y + ky - 1, ix = col - 1;
        double vv = 0.0;
        if ((unsigned)iy < 32u && (unsigned)ix < 32u)
            vv = (double)x[(((size_t)n * 3 + ci) * 32 + iy) * 32 + ix];
        xs[ci][ky][col] = vv;
    }
    __syncthreads();
    int co = threadIdx.x;
    double ws[27];
#pragma unroll
    for (int q = 0; q < 27; ++q) {
        float wv = cw[(size_t)co * 27 + q];   // q = (ci*3+ky)*3+kx
        ws[q] = (wv > 0.f) ? 1.0 : ((wv < 0.f) ? -1.0 : 0.0);
    }
    double inv = (double)g[co] / sqrt((double)v[co] + EPS);
    double addc = (double)cb[co] - (double)m[co];
    double bbv = (double)bb[co];
    ull* op = out + (size_t)blk * 32 * 6 + (co >> 6);
    for (int xx = 0; xx < 32; ++xx) {
        double acc = 0.0;
#pragma unroll
        for (int ci = 0; ci < 3; ++ci)
#pragma unroll
            for (int ky = 0; ky < 3; ++ky)
#pragma unroll
                for (int kx = 0; kx < 3; ++kx)
                    acc = fma(ws[(ci * 3 + ky) * 3 + kx], xs[ci][ky][xx + kx], acc);
        double tt = (acc + addc) * inv + bbv;
        ull mask = __ballot(tt > 0.0);
        if ((threadIdx.x & 63) == 0) op[(size_t)xx * 6] = mask;
    }
}

// ---------------------------------------------------------------------------
// Binary conv (+optional fused 2x2 maxpool) + bias + BN threshold + sign-pack.
// Block = 256 threads = one co-chunk (gridDim.y chunks); block processes PB
// consecutive pooled pixels along x. Activation window staged in LDS once
// (block-uniform), weights loaded lane-coalesced from [tap][kc][co] layout.
// Integer-exact: dot = valid_taps*64*KC - 2*popc(a^w), padding taps skipped.
// Pool applied to raw integer conv outputs (bias/BN after), matching ref.
// ---------------------------------------------------------------------------
template <int KC, int POOL, int PB>
__global__ __launch_bounds__(256) void binconv_kernel(
    const ull* __restrict__ act, const ull* __restrict__ wgt,
    const float* __restrict__ cb, const float* __restrict__ g,
    const float* __restrict__ bb, const float* __restrict__ m,
    const float* __restrict__ v, ull* __restrict__ out,
    int Hin, int Win, int Cout) {
    const int Hout = Hin / POOL, Wout = Win / POOL;
    const int WH = POOL + 2, WW = PB * POOL + 2;
    __shared__ ull lact[WH * WW * KC];
    int xb = blockIdx.x % (Wout / PB);
    int t = blockIdx.x / (Wout / PB);
    int yo = t % Hout;
    int n = t / Hout;
    int xo0 = xb * PB;
    int iy0 = yo * POOL - 1, ix0 = xo0 * POOL - 1;

    for (int i = threadIdx.x; i < WH * WW * KC; i += 256) {
        int kc = i % KC;
        int pp = i / KC;
        int wy = pp / WW, wx = pp % WW;
        int iy = iy0 + wy, ix = ix0 + wx;
        ull val = 0;
        if ((unsigned)iy < (unsigned)Hin && (unsigned)ix < (unsigned)Win)
            val = act[(((size_t)n * Hin + iy) * Win + ix) * KC + kc];
        lact[i] = val;
    }
    __syncthreads();

    int co = blockIdx.y * 256 + (int)threadIdx.x;
    if (co >= Cout) return;   // wave-uniform (Cout % 64 == 0); no later syncs

    double inv = (double)g[co] / sqrt((double)v[co] + EPS);
    double addc = (double)cb[co] - (double)m[co];
    double bbv = (double)bb[co];

    int tot[PB * POOL * POOL];
#pragma unroll
    for (int i = 0; i < PB * POOL * POOL; ++i) tot[i] = 0;

#pragma unroll 1
    for (int ky = 0; ky < 3; ++ky)
#pragma unroll 1
        for (int kx = 0; kx < 3; ++kx) {
            ull w[KC];
            const ull* wp = wgt + ((size_t)(ky * 3 + kx) * KC) * Cout + co;
#pragma unroll
            for (int kc = 0; kc < KC; ++kc) w[kc] = wp[(size_t)kc * Cout];
#pragma unroll
            for (int px = 0; px < PB; ++px)
#pragma unroll
                for (int dy = 0; dy < POOL; ++dy)
#pragma unroll
                    for (int dx = 0; dx < POOL; ++dx) {
                        int iy = iy0 + dy + ky;
                        int ix = ix0 + px * POOL + dx + kx;
                        if ((unsigned)iy < (unsigned)Hin &&
                            (unsigned)ix < (unsigned)Win) {
                            const ull* lp =
                                lact + ((dy + ky) * WW + (px * POOL + dx + kx)) * KC;
                            int mism = 0;
#pragma unroll
                            for (int kc = 0; kc < KC; ++kc)
                                mism += __popcll(lp[kc] ^ w[kc]);
                            tot[(px * POOL + dy) * POOL + dx] +=
                                KC * 64 - 2 * mism;
                        }
                    }
        }

    int KCOUT = Cout >> 6;
#pragma unroll
    for (int px = 0; px < PB; ++px) {
        int best = tot[px * POOL * POOL];
#pragma unroll
        for (int p = 1; p < POOL * POOL; ++p)
            best = max(best, tot[px * POOL * POOL + p]);
        double tt = ((double)best + addc) * inv + bbv;
        ull mask = __ballot(tt > 0.0);
        if ((threadIdx.x & 63) == 0)
            out[(size_t)((n * Hout + yo) * Wout + xo0 + px) * KCOUT + (co >> 6)] =
                mask;
    }
}

// ---------------------------------------------------------------------------
// Binary FC + bias + BN threshold + sign-pack. Grid = (N, Cout/256).
// Weights [kc][co] -> lane-coalesced; act loads are block-uniform (scalar).
// ---------------------------------------------------------------------------
template <int KCIN>
__global__ __launch_bounds__(256) void binfc_kernel(
    const ull* __restrict__ act, const ull* __restrict__ wgt,
    const float* __restrict__ lb, const float* __restrict__ g,
    const float* __restrict__ bb, const float* __restrict__ m,
    const float* __restrict__ v, ull* __restrict__ out, int Cout) {
    int n = blockIdx.x;
    int co = blockIdx.y * 256 + (int)threadIdx.x;
    const ull* ap = act + (size_t)n * KCIN;
    int mism = 0;
#pragma unroll 8
    for (int kc = 0; kc < KCIN; ++kc)
        mism += __popcll(ap[kc] ^ wgt[(size_t)kc * Cout + co]);
    int dot = 64 * KCIN - 2 * mism;
    double tt = ((double)dot + (double)lb[co] - (double)m[co]) *
                    ((double)g[co] / sqrt((double)v[co] + EPS)) +
                (double)bb[co];
    ull mask = __ballot(tt > 0.0);
    if (((int)threadIdx.x & 63) == 0)
        out[(size_t)n * (Cout >> 6) + ((unsigned)co >> 6)] = mask;
}

// ---------------------------------------------------------------------------
// Final FC3 (1024 -> 10) + affine-free BN + log_softmax, fp64. Grid = N.
// Weights stored [kc][co] (rows=10).
// ---------------------------------------------------------------------------
__global__ __launch_bounds__(64) void fc3_softmax(
    const ull* __restrict__ act, const ull* __restrict__ wgt,
    const float* __restrict__ lb, const float* __restrict__ m9,
    const float* __restrict__ v9, float* __restrict__ out) {
    int n = blockIdx.x;
    __shared__ double z[10];
    int j = threadIdx.x;
    if (j < 10) {
        const ull* ap = act + (size_t)n * 16;
        int mism = 0;
#pragma unroll
        for (int kc = 0; kc < 16; ++kc) mism += __popcll(ap[kc] ^ wgt[kc * 10 + j]);
        int dot = 1024 - 2 * mism;
        z[j] = ((double)dot + (double)lb[j] - (double)m9[j]) /
               sqrt((double)v9[j] + EPS);
    }
    __syncthreads();
    if (j < 10) {
        double mx = z[0];
        for (int k = 1; k < 10; ++k) mx = fmax(mx, z[k]);
        double s = 0.0;
        for (int k = 0; k < 10; ++k) s += exp(z[k] - mx);
        out[n * 10 + j] = (float)(z[j] - mx - log(s));
    }
}

// ---------------------------------------------------------------------------
extern "C" void kernel_launch(void* const* d_in, const int* in_sizes, int n_in,
                              void* d_out, int out_size, void* d_ws, size_t ws_size,
                              hipStream_t stream) {
    (void)in_sizes; (void)n_in; (void)out_size; (void)ws_size;

    const float* x   = (const float*)d_in[0];
    const float* cw[6], *cbv[6];
    for (int i = 0; i < 6; ++i) {
        cw[i]  = (const float*)d_in[1 + 2 * i];
        cbv[i] = (const float*)d_in[2 + 2 * i];
    }
    const float *G[8], *B[8], *M[8], *V[8];
    for (int i = 0; i < 8; ++i) {
        G[i] = (const float*)d_in[13 + 4 * i];
        B[i] = (const float*)d_in[14 + 4 * i];
        M[i] = (const float*)d_in[15 + 4 * i];
        V[i] = (const float*)d_in[16 + 4 * i];
    }
    const float* m9  = (const float*)d_in[45];
    const float* v9  = (const float*)d_in[46];
    const float* lw1 = (const float*)d_in[47];
    const float* lb1 = (const float*)d_in[48];
    const float* lw2 = (const float*)d_in[49];
    const float* lb2 = (const float*)d_in[50];
    const float* lw3 = (const float*)d_in[51];
    const float* lb3 = (const float*)d_in[52];
    float* outp = (float*)d_out;

    ull* ws = (ull*)d_ws;
    // word offsets (8B units)
    ull* W2  = ws + 0;        // 20736
    ull* W3  = ws + 20736;    // 41472
    ull* W4  = ws + 62208;    // 82944
    ull* W5  = ws + 145152;   // 165888
    ull* W6  = ws + 311040;   // 110592
    ull* FW1 = ws + 421632;   // 131072
    ull* FW2 = ws + 552704;   // 16384
    ull* FW3 = ws + 569088;   // 160
    ull* A1  = ws + 569248;   // 196608 : 32x32x32 pixels x 6 words
    ull* A2  = ws + 765856;   // 49152  : 32x16x16 x 6
    ull* A3  = ws + 815008;   // 98304  : 32x16x16 x 12
    ull* A4  = ws + 913312;   // 24576  : 32x8x8 x 12
    ull* A5  = ws + 937888;   // 49152  : 32x8x8 x 24
    ull* A6  = ws + 987040;   // 4096   : 32x4x4 x 8
    ull* F1  = ws + 991136;   // 512    : 32 x 16
    ull* F2  = ws + 991648;   // 512    : 32 x 16
    // total 992160 words = ~7.94 MB

    // ---- pack weights ----
    pack_conv_w<<<(20736 + 255) / 256, 256, 0, stream>>>(cw[1], W2, 384, 384);
    pack_conv_w<<<(41472 + 255) / 256, 256, 0, stream>>>(cw[2], W3, 768, 384);
    pack_conv_w<<<(82944 + 255) / 256, 256, 0, stream>>>(cw[3], W4, 768, 768);
    pack_conv_w<<<(165888 + 255) / 256, 256, 0, stream>>>(cw[4], W5, 1536, 768);
    pack_conv_w<<<(110592 + 255) / 256, 256, 0, stream>>>(cw[5], W6, 512, 1536);
    pack_lw1<<<(131072 + 255) / 256, 256, 0, stream>>>(lw1, FW1);
    pack_lw_lin<<<(16384 + 255) / 256, 256, 0, stream>>>(lw2, FW2, 1024, 16);
    pack_lw_lin<<<1, 256, 0, stream>>>(lw3, FW3, 10, 16);

    // ---- layer 1: real conv, fp64, LDS-staged ----
    conv1_bn_sign<<<32 * 32, 384, 0, stream>>>(x, cw[0], cbv[0], G[0], B[0],
                                               M[0], V[0], A1);
    // ---- binary conv stack ----
    binconv_kernel<6, 2, 4><<<dim3(2048, 2), 256, 0, stream>>>(
        A1, W2, cbv[1], G[1], B[1], M[1], V[1], A2, 32, 32, 384);
    binconv_kernel<6, 1, 4><<<dim3(2048, 3), 256, 0, stream>>>(
        A2, W3, cbv[2], G[2], B[2], M[2], V[2], A3, 16, 16, 768);
    binconv_kernel<12, 2, 4><<<dim3(512, 3), 256, 0, stream>>>(
        A3, W4, cbv[3], G[3], B[3], M[3], V[3], A4, 16, 16, 768);
    binconv_kernel<12, 1, 4><<<dim3(512, 6), 256, 0, stream>>>(
        A4, W5, cbv[4], G[4], B[4], M[4], V[4], A5, 8, 8, 1536);
    binconv_kernel<24, 2, 2><<<dim3(256, 2), 256, 0, stream>>>(
        A5, W6, cbv[5], G[5], B[5], M[5], V[5], A6, 8, 8, 512);
    // ---- FC stack ----
    binfc_kernel<128><<<dim3(32, 4), 256, 0, stream>>>(A6, FW1, lb1, G[6], B[6],
                                                       M[6], V[6], F1, 1024);
    binfc_kernel<16><<<dim3(32, 4), 256, 0, stream>>>(F1, FW2, lb2, G[7], B[7],
                                                      M[7], V[7], F2, 1024);
    fc3_softmax<<<32, 64, 0, stream>>>(F2, FW3, lb3, m9, v9, outp);
}